// Round 5
// baseline (421.770 us; speedup 1.0000x reference)
//
#include <hip/hip_runtime.h>

// SpikingSiameseNetwork forward, MI355X/gfx950.
// prep(3-way bf16 weight split) -> GEMM1 -> LIF1 -> GEMM2 -> LIF2+tail.
// Numerics: activations exactly {0,1}; weights split into 3 bf16 parts summed
// in fp32 MFMA accumulator => fp32-exact (absmax 0.0 through R4).
// R2: XOR swizzle -> bank conflicts 0. R3: 256-tile reg-staged spilled. R4:
// schedule reorder null at 513 TF = reg-staged 2-phase ceiling (m230/m233).
// R5: global_load_lds staging (T2 via pre-swizzled per-lane SOURCE, m173;
//     LDS dest linear), fp32-A staged raw + packed at frag-read. No setprio
//     (T5 null at 2ph). GEMM2 regridded to 1600 blocks / 3 blk/CU.

typedef short bf16x8 __attribute__((ext_vector_type(8)));
typedef float f32x4 __attribute__((ext_vector_type(4)));

#define RBIG 51200  // BS(2048) * T(25)

__device__ __forceinline__ void glds16(const void* g, void* l) {
    __builtin_amdgcn_global_load_lds((const __attribute__((address_space(1))) void*)g,
                                     (__attribute__((address_space(3))) void*)l, 16, 0, 0);
}

// ---------------- prep: split fp32 weights into 3 bf16 parts --------------
__global__ void prep_w(const float* __restrict__ Wa1, const float* __restrict__ Wv1,
                       const float* __restrict__ Wa2, const float* __restrict__ Wv2,
                       unsigned short* __restrict__ W1s, unsigned short* __restrict__ W2s) {
    int idx = blockIdx.x * 256 + threadIdx.x;  // total 327680 exactly
    float w;
    unsigned short* dst;
    int K, k;
    if (idx < 262144) {
        int p = idx >> 17, rem = idx & 131071;
        int n = rem >> 9; k = rem & 511; K = 512;
        const float* src = p ? Wv1 : Wa1;
        w = src[(size_t)n * 512 + k];
        dst = W1s + (size_t)p * 256 * 1536 + (size_t)n * 1536;
    } else {
        int j = idx - 262144;
        int p = j >> 15, rem = j & 32767;
        int n = rem >> 8; k = rem & 255; K = 256;
        const float* src = p ? Wv2 : Wa2;
        w = src[(size_t)n * 256 + k];
        dst = W2s + (size_t)p * 128 * 768 + (size_t)n * 768;
    }
    unsigned int u  = __float_as_uint(w);
    unsigned int hi = u & 0xFFFF0000u;
    float r1 = w - __uint_as_float(hi);
    unsigned int mi = __float_as_uint(r1) & 0xFFFF0000u;
    float r2 = r1 - __uint_as_float(mi);
    dst[k]         = (unsigned short)(hi >> 16);
    dst[K + k]     = (unsigned short)(mi >> 16);
    dst[2 * K + k] = (unsigned short)(__float_as_uint(r2) >> 16);
}

// ---------------- GEMM: C[51200 x NT] = A * W'^T ---------------------------
// global_load_lds staging, pre-swizzled per-lane source (16B granule XOR:
// src_slot = lds_slot ^ (row&7)); linear LDS dest. Frag reads apply the same
// XOR. A is fp32 when AF32 (packed to bf16 at frag read; exact for {0,1}).
// 2-phase loop: [issue gload_lds c+1 -> other buf] [frag reads + MFMA on c]
// [__syncthreads = vmcnt/lgkm drain + barrier].
template <int KSRC, int NT, int BM, int BN, int NTHR, int WMW, int WNW, int MINW, bool AF32>
__global__ __launch_bounds__(NTHR, MINW) void gemmG(
    const void* __restrict__ A0, const void* __restrict__ A1,
    const unsigned short* __restrict__ Ws, float* __restrict__ C) {
    constexpr int KE     = 3 * KSRC;
    constexpr int NC     = 3 * (KSRC / 64);
    constexpr int MFR    = BM / WMW / 16;
    constexpr int NFR    = BN / WNW / 16;
    constexpr int AESZ   = AF32 ? 4 : 2;
    constexpr int ABYTES = BM * 64 * AESZ;
    constexpr int BBYTES = BN * 64 * 2;
    constexpr int NAG    = ABYTES / 16 / NTHR;  // A gloads / thread / chunk
    constexpr int NBG    = BBYTES / 16 / NTHR;

    __shared__ __align__(1024) char lds[2 * ABYTES + 2 * BBYTES];

    const int tid  = threadIdx.x, lane = tid & 63, wave = tid >> 6;
    const int wm   = wave / WNW, wn = wave % WNW;
    const int bx   = blockIdx.x, bz = blockIdx.z;
    const size_t row0 = (size_t)bx * BM;

    const char* Abase = (const char*)(bz ? A1 : A0) + row0 * KSRC * AESZ;
    const char* Bbase = (const char*)Ws + (size_t)bz * NT * KE * 2;

    // per-thread source offsets (chunk-relative, bytes) + LDS dest offsets
    size_t offA[NAG];
    int dA[NAG];
#pragma unroll
    for (int j = 0; j < NAG; ++j) {
        int G = tid + j * NTHR;
        int row, sl;
        if constexpr (AF32) { row = G >> 4; sl = G & 15; }
        else                { row = G >> 3; sl = G & 7; }
        offA[j] = (size_t)row * KSRC * AESZ + (size_t)((sl ^ (row & 7)) << 4);
        dA[j]   = wave * 1024 + j * NTHR * 16;
    }
    size_t offB[NBG];
    int dB[NBG];
#pragma unroll
    for (int j = 0; j < NBG; ++j) {
        int G = tid + j * NTHR;
        int n = G >> 3, sl = G & 7;
        offB[j] = (size_t)n * KE * 2 + (size_t)((sl ^ (n & 7)) << 4);
        dB[j]   = wave * 1024 + j * NTHR * 16;
    }

    auto stageA = [&](int kb) {
        const char* s = Abase + (size_t)kb * 64 * AESZ;
        char* d = lds + (kb & 1) * ABYTES;
#pragma unroll
        for (int j = 0; j < NAG; ++j) glds16(s + offA[j], d + dA[j]);
    };
    auto stageB = [&](int kb, int sh, int buf) {
        const char* s = Bbase + ((size_t)sh * KSRC + (size_t)kb * 64) * 2;
        char* d = lds + 2 * ABYTES + buf * BBYTES;
#pragma unroll
        for (int j = 0; j < NBG; ++j) glds16(s + offB[j], d + dB[j]);
    };

    f32x4 acc[MFR][NFR];
    f32x4 zz = {0.f, 0.f, 0.f, 0.f};
#pragma unroll
    for (int i = 0; i < MFR; ++i)
#pragma unroll
        for (int j = 0; j < NFR; ++j) acc[i][j] = zz;

    // prologue
    stageA(0);
    stageB(0, 0, 0);
    __syncthreads();

    const int rfr = lane & 15;
    int kb = 0, s = 0;
    for (int c = 0; c < NC; ++c) {
        int s1 = (s == 2) ? 0 : s + 1;
        int kb1 = (s1 == 0) ? kb + 1 : kb;
        if (c + 1 < NC) {
            stageB(kb1, s1, (c + 1) & 1);
            if (s1 == 0) stageA(kb1);
        }

        const char* Ab = lds + (kb & 1) * ABYTES;
        const unsigned short* Bb = (const unsigned short*)(lds + 2 * ABYTES + (c & 1) * BBYTES);
#pragma unroll
        for (int ks = 0; ks < 2; ++ks) {
            const int kbase = ks * 32 + ((lane >> 4) << 3);
            bf16x8 bb[NFR];
#pragma unroll
            for (int ni = 0; ni < NFR; ++ni) {
                int n = wn * (BN / WNW) + ni * 16 + rfr;
                bb[ni] = *(const bf16x8*)&Bb[(n * 64 + kbase) ^ ((n & 7) << 3)];
            }
#pragma unroll
            for (int mi = 0; mi < MFR; ++mi) {
                int r = wm * (BM / WMW) + mi * 16 + rfr;
                bf16x8 av;
                if constexpr (AF32) {
                    const float* Af = (const float*)Ab;
                    int e1 = (r * 64 + kbase) ^ ((r & 7) << 2);
                    uint4 ua = *(const uint4*)&Af[e1];
                    uint4 ub = *(const uint4*)&Af[e1 ^ 4];
                    uint4 w;
                    w.x = (ua.y & 0xFFFF0000u) | (ua.x >> 16);
                    w.y = (ua.w & 0xFFFF0000u) | (ua.z >> 16);
                    w.z = (ub.y & 0xFFFF0000u) | (ub.x >> 16);
                    w.w = (ub.w & 0xFFFF0000u) | (ub.z >> 16);
                    av = __builtin_bit_cast(bf16x8, w);
                } else {
                    const unsigned short* Au = (const unsigned short*)Ab;
                    av = *(const bf16x8*)&Au[(r * 64 + kbase) ^ ((r & 7) << 3)];
                }
#pragma unroll
                for (int ni = 0; ni < NFR; ++ni)
                    acc[mi][ni] = __builtin_amdgcn_mfma_f32_16x16x32_bf16(
                        av, bb[ni], acc[mi][ni], 0, 0, 0);
            }
        }
        __syncthreads();
        kb = kb1; s = s1;
    }

    // epilogue: C/D layout col=lane&15, row=(lane>>4)*4+reg (m89-verified)
    float* Cp = C + (size_t)bz * RBIG * NT;
    int r4 = ((lane >> 4) << 2), cl = lane & 15;
#pragma unroll
    for (int mi = 0; mi < MFR; ++mi)
#pragma unroll
        for (int ni = 0; ni < NFR; ++ni) {
            size_t col = (size_t)wn * (BN / WNW) + ni * 16 + cl;
#pragma unroll
            for (int j = 0; j < 4; ++j) {
                size_t row = row0 + wm * (BM / WMW) + mi * 16 + r4 + j;
                Cp[row * NT + col] = acc[mi][ni][j];
            }
        }
}

// ---------------- LIF layer 1: scan over t, emit bf16 spikes ---------------
__global__ void lif1_k(const float* __restrict__ cur, const float* __restrict__ ba1,
                       const float* __restrict__ bv1, unsigned int* __restrict__ spk) {
    int r = blockIdx.x, p = blockIdx.y, d = threadIdx.x;  // 128 threads
    const float* c0 = cur + ((size_t)p * RBIG + (size_t)r * 25) * 256 + 2 * d;
    const float* bias = p ? bv1 : ba1;
    float b0 = bias[2 * d], b1 = bias[2 * d + 1];
    float2 cv[25];
#pragma unroll
    for (int t = 0; t < 25; ++t) cv[t] = *(const float2*)(c0 + (size_t)t * 256);
    unsigned int* sp = spk + ((size_t)p * RBIG + (size_t)r * 25) * 128 + d;
    float m0 = 0.f, m1 = 0.f;
#pragma unroll
    for (int t = 0; t < 25; ++t) {
        float r0 = (m0 > 1.f) ? 1.f : 0.f;  // reset from PREVIOUS mem
        float r1 = (m1 > 1.f) ? 1.f : 0.f;
        m0 = 0.9f * m0 + (cv[t].x + b0) - r0;
        m1 = 0.9f * m1 + (cv[t].y + b1) - r1;
        unsigned int w = (m0 > 1.f ? 0x3F80u : 0u) | (m1 > 1.f ? 0x3F800000u : 0u);
        sp[(size_t)t * 128] = w;
    }
}

// -------- fused LIF2 + normalize + mean (one block per output batch b) -----
__global__ void tail_k(const float* __restrict__ cur2, const float* __restrict__ ba2,
                       const float* __restrict__ bv2, float* __restrict__ out) {
    int b = blockIdx.x, d = threadIdx.x;  // 256 threads, d = output dim
    int p = d >> 7, e = d & 127;
    const float* bias = p ? bv2 : ba2;
    float bo = bias[e];
    __shared__ float part[4];
    float acc = 0.f;
    for (int s = 0; s < 8; ++s) {
        int r = b * 8 + s;
        const float* c0 = cur2 + ((size_t)p * RBIG + (size_t)r * 25) * 128 + e;
        float cv[25];
#pragma unroll
        for (int t = 0; t < 25; ++t) cv[t] = c0[(size_t)t * 128];
        float m = 0.f;
#pragma unroll
        for (int t = 0; t < 25; ++t) {
            float rs = (m > 1.f) ? 1.f : 0.f;
            m = 0.9f * m + (cv[t] + bo) - rs;
        }
        float v = (m > 1.f) ? 1.f : 0.f;
        float sq = v;  // v in {0,1}: v*v == v; sum order-exact
#pragma unroll
        for (int off = 32; off > 0; off >>= 1) sq += __shfl_down(sq, off);
        if ((d & 63) == 0) part[d >> 6] = sq;
        __syncthreads();
        float nrm = sqrtf(part[0] + part[1] + part[2] + part[3]);
        acc += v / fmaxf(nrm, 1e-12f);
        __syncthreads();  // protect part[] before next s
    }
    out[(size_t)b * 256 + d] = acc * 0.125f;
}

extern "C" void kernel_launch(void* const* d_in, const int* in_sizes, int n_in,
                              void* d_out, int out_size, void* d_ws, size_t ws_size,
                              hipStream_t stream) {
    const float* a_seq = (const float*)d_in[0];
    const float* v_seq = (const float*)d_in[1];
    const float* W_a1  = (const float*)d_in[2];
    const float* b_a1  = (const float*)d_in[3];
    const float* W_a2  = (const float*)d_in[4];
    const float* b_a2  = (const float*)d_in[5];
    const float* W_v1  = (const float*)d_in[6];
    const float* b_v1  = (const float*)d_in[7];
    const float* W_v2  = (const float*)d_in[8];
    const float* b_v2  = (const float*)d_in[9];

    char* ws = (char*)d_ws;  // ~159.3 MB used
    unsigned short* W1s  = (unsigned short*)(ws);              // 1,572,864 B
    unsigned short* W2s  = (unsigned short*)(ws + 1572864);    //   393,216 B
    unsigned short* spk1 = (unsigned short*)(ws + 1966080);    // 52,428,800 B
    float*          curb = (float*)(ws + 54394880);            // 104,857,600 B
    float*          out  = (float*)d_out;

    prep_w<<<1280, 256, 0, stream>>>(W_a1, W_v1, W_a2, W_v2, W1s, W2s);

    // layer 1: cur1[p][51200][256]; BM=128 BN=256, 512 thr (8 waves 2x4),
    // LDS 128KB (1 blk/CU), 800 blocks
    gemmG<512, 256, 128, 256, 512, 2, 4, 2, true>
        <<<dim3(400, 1, 2), 512, 0, stream>>>(a_seq, v_seq, W1s, curb);
    lif1_k<<<dim3(2048, 2), 128, 0, stream>>>(curb, b_a1, b_v1, (unsigned int*)spk1);

    // layer 2: cur2[p][51200][128]; BM=64 BN=128, 256 thr (4 waves 2x2),
    // LDS 48KB (3 blk/CU), 1600 blocks
    gemmG<256, 128, 64, 128, 256, 2, 2, 3, false>
        <<<dim3(800, 1, 2), 256, 0, stream>>>(
        spk1, spk1 + (size_t)RBIG * 256, W2s, curb);

    tail_k<<<256, 256, 0, stream>>>(curb, b_a2, b_v2, out);
}

// Round 6
// 363.252 us; speedup vs baseline: 1.1611x; 1.1611x over previous
//
#include <hip/hip_runtime.h>

// SpikingSiameseNetwork forward, MI355X/gfx950.
// prep(3-way bf16 weight split) -> GEMM1 -> LIF1 -> GEMM2 -> LIF2+tail.
// Numerics: activations exactly {0,1}; weights split into 3 bf16 parts summed
// in fp32 MFMA accumulator => fp32-exact (absmax 0.0 through R5).
// R2: XOR swizzle -> conflicts 0. R4: schedule reorder null (reg-staged 2ph
// ceiling). R5: gload_lds correct but 128KB LDS -> 1 blk/CU killed it (196us).
// R6: m97 geometry: 128x128 tile, 256thr/4 waves, SINGLE-buffered 48KB LDS
//     (3 blk/CU -> cross-block overlap hides barrier drain, m114), gload_lds
//     w16 with pre-swizzled source, A staged once per kb, XCD-swizzled grid.
//     SQ_LDS_BANK_CONFLICT ~1e7 here is gload_lds DMA accounting (m98), benign.

typedef short bf16x8 __attribute__((ext_vector_type(8)));
typedef float f32x4 __attribute__((ext_vector_type(4)));

#define RBIG 51200  // BS(2048) * T(25)

__device__ __forceinline__ void glds16(const void* g, void* l) {
    __builtin_amdgcn_global_load_lds((const __attribute__((address_space(1))) void*)g,
                                     (__attribute__((address_space(3))) void*)l, 16, 0, 0);
}

// ---------------- prep: split fp32 weights into 3 bf16 parts --------------
__global__ void prep_w(const float* __restrict__ Wa1, const float* __restrict__ Wv1,
                       const float* __restrict__ Wa2, const float* __restrict__ Wv2,
                       unsigned short* __restrict__ W1s, unsigned short* __restrict__ W2s) {
    int idx = blockIdx.x * 256 + threadIdx.x;  // total 327680 exactly
    float w;
    unsigned short* dst;
    int K, k;
    if (idx < 262144) {
        int p = idx >> 17, rem = idx & 131071;
        int n = rem >> 9; k = rem & 511; K = 512;
        const float* src = p ? Wv1 : Wa1;
        w = src[(size_t)n * 512 + k];
        dst = W1s + (size_t)p * 256 * 1536 + (size_t)n * 1536;
    } else {
        int j = idx - 262144;
        int p = j >> 15, rem = j & 32767;
        int n = rem >> 8; k = rem & 255; K = 256;
        const float* src = p ? Wv2 : Wa2;
        w = src[(size_t)n * 256 + k];
        dst = W2s + (size_t)p * 128 * 768 + (size_t)n * 768;
    }
    unsigned int u  = __float_as_uint(w);
    unsigned int hi = u & 0xFFFF0000u;
    float r1 = w - __uint_as_float(hi);
    unsigned int mi = __float_as_uint(r1) & 0xFFFF0000u;
    float r2 = r1 - __uint_as_float(mi);
    dst[k]         = (unsigned short)(hi >> 16);
    dst[K + k]     = (unsigned short)(mi >> 16);
    dst[2 * K + k] = (unsigned short)(__float_as_uint(r2) >> 16);
}

// ---------------- GEMM: C[51200 x NT] = A * W'^T ---------------------------
// m97-style: BM x BN tile, BK=64, 4 waves (2x2), single-buffered LDS,
// gload_lds(16) staging with pre-swizzled per-lane source (read applies the
// same XOR; involution verified R5, absmax 0). A staged once per kb, reused
// across the 3 weight splits. 2 barriers per chunk; pipelining comes from
// 3-4 co-resident blocks/CU (m114).
template <int KSRC, int NT, int BM, int BN, int MINW, bool AF32>
__global__ __launch_bounds__(256, MINW) void gemmS(
    const void* __restrict__ A0, const void* __restrict__ A1,
    const unsigned short* __restrict__ Ws, float* __restrict__ C) {
    constexpr int KE   = 3 * KSRC;
    constexpr int NKB  = KSRC / 64;
    constexpr int MFR  = BM / 2 / 16;
    constexpr int NFR  = BN / 2 / 16;
    constexpr int AESZ = AF32 ? 4 : 2;
    constexpr int NBY  = NT / BN;
    constexpr int NAG  = BM * 64 * AESZ / 16 / 256;  // A gloads / thread
    constexpr int NBG  = BN * 64 * 2 / 16 / 256;     // B gloads / thread
    constexpr int GPRA = 64 * AESZ / 16;             // A granules per row

    __shared__ __align__(1024) char Al[BM * 64 * AESZ];
    __shared__ __align__(1024) unsigned short Bl[BN * 64];

    const int tid  = threadIdx.x, lane = tid & 63, wave = tid >> 6;
    const int wm   = wave >> 1, wn = wave & 1;

    // XCD-aware bijective swizzle (nwg % 8 == 0); low bits = (by, bz) so
    // consecutive lids within an XCD share the A-panel (bx).
    const int nwg = gridDim.x;
    const int orig = blockIdx.x;
    const int lid = (orig & 7) * (nwg >> 3) + (orig >> 3);
    const int by = lid % NBY;
    const int t0 = lid / NBY;
    const int bz = t0 & 1;
    const int bx = t0 >> 1;
    const size_t row0 = (size_t)bx * BM;

    const char* Abase = (const char*)(bz ? A1 : A0) + row0 * KSRC * AESZ;
    const char* Bbase = (const char*)Ws + ((size_t)bz * NT + (size_t)by * BN) * KE * 2;

    // per-thread staging offsets (j-stride is compile-time constant)
    const int rowA0 = tid / GPRA, slA = tid % GPRA;
    const size_t offA0 = (size_t)rowA0 * KSRC * AESZ + (size_t)((slA ^ (rowA0 & 7)) << 4);
    const int rowB0 = tid >> 3, slB = tid & 7;
    const size_t offB0 = (size_t)rowB0 * KE * 2 + (size_t)((slB ^ (rowB0 & 7)) << 4);
    const int dst0 = wave * 1024;

    auto stageA = [&](int kb) {
        const char* s = Abase + (size_t)kb * 64 * AESZ + offA0;
        char* d = Al + dst0;
#pragma unroll
        for (int j = 0; j < NAG; ++j)
            glds16(s + (size_t)j * (64 * KSRC), d + j * 4096);
    };
    auto stageB = [&](int kb, int sp) {
        const char* s = Bbase + ((size_t)sp * KSRC + (size_t)kb * 64) * 2 + offB0;
        char* d = (char*)Bl + dst0;
#pragma unroll
        for (int j = 0; j < NBG; ++j)
            glds16(s + (size_t)j * (64 * KE), d + j * 4096);
    };

    f32x4 acc[MFR][NFR];
    f32x4 zz = {0.f, 0.f, 0.f, 0.f};
#pragma unroll
    for (int i = 0; i < MFR; ++i)
#pragma unroll
        for (int j = 0; j < NFR; ++j) acc[i][j] = zz;

    const int rfr = lane & 15;
    for (int kb = 0; kb < NKB; ++kb) {
#pragma unroll 1
        for (int s = 0; s < 3; ++s) {
            if (s == 0) stageA(kb);
            stageB(kb, s);
            __syncthreads();  // vmcnt drain + visibility
#pragma unroll
            for (int ks = 0; ks < 2; ++ks) {
                const int kbase = ks * 32 + ((lane >> 4) << 3);
                bf16x8 bb[NFR];
#pragma unroll
                for (int ni = 0; ni < NFR; ++ni) {
                    int n = wn * (BN / 2) + ni * 16 + rfr;
                    bb[ni] = *(const bf16x8*)&Bl[(n * 64 + kbase) ^ ((n & 7) << 3)];
                }
#pragma unroll
                for (int mi = 0; mi < MFR; ++mi) {
                    int r = wm * (BM / 2) + mi * 16 + rfr;
                    bf16x8 av;
                    if constexpr (AF32) {
                        const float* Af = (const float*)Al;
                        int e1 = (r * 64 + kbase) ^ ((r & 7) << 2);
                        uint4 ua = *(const uint4*)&Af[e1];
                        uint4 ub = *(const uint4*)&Af[e1 ^ 4];
                        uint4 w;
                        w.x = (ua.y & 0xFFFF0000u) | (ua.x >> 16);
                        w.y = (ua.w & 0xFFFF0000u) | (ua.z >> 16);
                        w.z = (ub.y & 0xFFFF0000u) | (ub.x >> 16);
                        w.w = (ub.w & 0xFFFF0000u) | (ub.z >> 16);
                        av = __builtin_bit_cast(bf16x8, w);
                    } else {
                        const unsigned short* Au = (const unsigned short*)Al;
                        av = *(const bf16x8*)&Au[(r * 64 + kbase) ^ ((r & 7) << 3)];
                    }
#pragma unroll
                    for (int ni = 0; ni < NFR; ++ni)
                        acc[mi][ni] = __builtin_amdgcn_mfma_f32_16x16x32_bf16(
                            av, bb[ni], acc[mi][ni], 0, 0, 0);
                }
            }
            __syncthreads();  // readers done before next stage overwrites
        }
    }

    // epilogue: C/D layout col=lane&15, row=(lane>>4)*4+reg (m89-verified)
    float* Cp = C + (size_t)bz * RBIG * NT;
    int r4 = ((lane >> 4) << 2), cl = lane & 15;
#pragma unroll
    for (int mi = 0; mi < MFR; ++mi)
#pragma unroll
        for (int ni = 0; ni < NFR; ++ni) {
            size_t col = (size_t)by * BN + wn * (BN / 2) + ni * 16 + cl;
#pragma unroll
            for (int j = 0; j < 4; ++j) {
                size_t row = row0 + wm * (BM / 2) + mi * 16 + r4 + j;
                Cp[row * NT + col] = acc[mi][ni][j];
            }
        }
}

// ---------------- LIF layer 1: scan over t, emit bf16 spikes ---------------
__global__ void lif1_k(const float* __restrict__ cur, const float* __restrict__ ba1,
                       const float* __restrict__ bv1, unsigned int* __restrict__ spk) {
    int r = blockIdx.x, p = blockIdx.y, d = threadIdx.x;  // 128 threads
    const float* c0 = cur + ((size_t)p * RBIG + (size_t)r * 25) * 256 + 2 * d;
    const float* bias = p ? bv1 : ba1;
    float b0 = bias[2 * d], b1 = bias[2 * d + 1];
    float2 cv[25];
#pragma unroll
    for (int t = 0; t < 25; ++t) cv[t] = *(const float2*)(c0 + (size_t)t * 256);
    unsigned int* sp = spk + ((size_t)p * RBIG + (size_t)r * 25) * 128 + d;
    float m0 = 0.f, m1 = 0.f;
#pragma unroll
    for (int t = 0; t < 25; ++t) {
        float r0 = (m0 > 1.f) ? 1.f : 0.f;  // reset from PREVIOUS mem
        float r1 = (m1 > 1.f) ? 1.f : 0.f;
        m0 = 0.9f * m0 + (cv[t].x + b0) - r0;
        m1 = 0.9f * m1 + (cv[t].y + b1) - r1;
        unsigned int w = (m0 > 1.f ? 0x3F80u : 0u) | (m1 > 1.f ? 0x3F800000u : 0u);
        sp[(size_t)t * 128] = w;
    }
}

// -------- fused LIF2 + normalize + mean (one block per output batch b) -----
__global__ void tail_k(const float* __restrict__ cur2, const float* __restrict__ ba2,
                       const float* __restrict__ bv2, float* __restrict__ out) {
    int b = blockIdx.x, d = threadIdx.x;  // 256 threads, d = output dim
    int p = d >> 7, e = d & 127;
    const float* bias = p ? bv2 : ba2;
    float bo = bias[e];
    __shared__ float part[4];
    float acc = 0.f;
    for (int s = 0; s < 8; ++s) {
        int r = b * 8 + s;
        const float* c0 = cur2 + ((size_t)p * RBIG + (size_t)r * 25) * 128 + e;
        float cv[25];
#pragma unroll
        for (int t = 0; t < 25; ++t) cv[t] = c0[(size_t)t * 128];
        float m = 0.f;
#pragma unroll
        for (int t = 0; t < 25; ++t) {
            float rs = (m > 1.f) ? 1.f : 0.f;
            m = 0.9f * m + (cv[t] + bo) - rs;
        }
        float v = (m > 1.f) ? 1.f : 0.f;
        float sq = v;  // v in {0,1}: v*v == v; sum order-exact
#pragma unroll
        for (int off = 32; off > 0; off >>= 1) sq += __shfl_down(sq, off);
        if ((d & 63) == 0) part[d >> 6] = sq;
        __syncthreads();
        float nrm = sqrtf(part[0] + part[1] + part[2] + part[3]);
        acc += v / fmaxf(nrm, 1e-12f);
        __syncthreads();  // protect part[] before next s
    }
    out[(size_t)b * 256 + d] = acc * 0.125f;
}

extern "C" void kernel_launch(void* const* d_in, const int* in_sizes, int n_in,
                              void* d_out, int out_size, void* d_ws, size_t ws_size,
                              hipStream_t stream) {
    const float* a_seq = (const float*)d_in[0];
    const float* v_seq = (const float*)d_in[1];
    const float* W_a1  = (const float*)d_in[2];
    const float* b_a1  = (const float*)d_in[3];
    const float* W_a2  = (const float*)d_in[4];
    const float* b_a2  = (const float*)d_in[5];
    const float* W_v1  = (const float*)d_in[6];
    const float* b_v1  = (const float*)d_in[7];
    const float* W_v2  = (const float*)d_in[8];
    const float* b_v2  = (const float*)d_in[9];

    char* ws = (char*)d_ws;  // ~159.3 MB used
    unsigned short* W1s  = (unsigned short*)(ws);              // 1,572,864 B
    unsigned short* W2s  = (unsigned short*)(ws + 1572864);    //   393,216 B
    unsigned short* spk1 = (unsigned short*)(ws + 1966080);    // 52,428,800 B
    float*          curb = (float*)(ws + 54394880);            // 104,857,600 B
    float*          out  = (float*)d_out;

    prep_w<<<1280, 256, 0, stream>>>(W_a1, W_v1, W_a2, W_v2, W1s, W2s);

    // layer 1: cur1[p][51200][256]; BM=128 BN=128 (by=2), 1600 blocks,
    // LDS 48KB single-buffered -> 3 blk/CU
    gemmS<512, 256, 128, 128, 3, true><<<1600, 256, 0, stream>>>(
        a_seq, v_seq, W1s, curb);
    lif1_k<<<dim3(2048, 2), 128, 0, stream>>>(curb, b_a1, b_v1, (unsigned int*)spk1);

    // layer 2: cur2[p][51200][128]; BM=64 BN=128, 1600 blocks,
    // LDS 24KB single-buffered -> 4+ blk/CU
    gemmS<256, 128, 64, 128, 4, false><<<1600, 256, 0, stream>>>(
        spk1, spk1 + (size_t)RBIG * 256, W2s, curb);

    tail_k<<<256, 256, 0, stream>>>(curb, b_a2, b_v2, out);
}